// Round 11
// baseline (271.529 us; speedup 1.0000x reference)
//
#include <hip/hip_runtime.h>

// DCGRU cell, MI355X.  (R10 base; gconv -> 512-thread 256x128 8-wave tile.)
//   Diffusion intermediates TRANSPOSED: XT[col = f*64+b][node n] in bf16.
//   sq_gemm (once): SS_z = S_z @ S_z via A = S_z^T, Xi = S_z on a BK=64
//     double-buffered deep pipe (64KB LDS, 16 K-steps, counted vmcnt(8)).
//   gconv_gemm: 528 blocks x 512 threads, 256x128 tile, 8 waves (4M x 2N,
//     each wave a 64x64 quadrant = acc[4][4], identical math to the verified
//     128x128 core). BK=32, TRIPLE-buffered LDS (72KB -> 2 blocks/CU =
//     16 waves/CU, up from 12), counted vmcnt(3) (never 0 in main loop).
//     XOR swizzle via pre-swizzled GLOBAL source. Staged bytes/output DROPS
//     vs 128x128 (24 vs 32 B). XCD-bijective decode (528%8==0).
//     Chebyshev "2Y - X0" folded into projection weights.
//   proj1/proj2: A staged in LDS [n][kp] stride 360 (5n%8 bijective ->
//     conflict-free ds_read_b128 A-frags). Burst staging. Wave split:
//     32 n-rows x half the o-outputs. WF in fragment order (coalesced).
//   d_out doubles as u-buffer.

typedef unsigned short u16;
typedef unsigned int u32;
typedef short s16x8 __attribute__((ext_vector_type(8)));
typedef float f32x4 __attribute__((ext_vector_type(4)));
typedef u16 u16x4 __attribute__((ext_vector_type(4)));

#define NN 1024
#define NB 64
#define NF 66
#define NCOLS 4224  // NF*NB
#define KPAD 352    // 330 padded to 11*32
#define ASTRIDE 360 // proj A-LDS row stride in u16 (720B, 5n%8 bijection)

__device__ __forceinline__ u16 f2bf(float f) {
  u32 u = __builtin_bit_cast(u32, f);
  u = (u + 0x7fffu + ((u >> 16) & 1u)) >> 16;  // RNE
  return (u16)u;
}
__device__ __forceinline__ float bf2f(u16 h) {
  u32 u = ((u32)h) << 16;
  return __builtin_bit_cast(float, u);
}

__device__ __forceinline__ void gload16(const void* g, void* l) {
  __builtin_amdgcn_global_load_lds(
      (const __attribute__((address_space(1))) u32*)g,
      (__attribute__((address_space(3))) u32*)l, 16, 0, 0);
}

// counted-vmcnt barrier: own oldest loads landed -> barrier -> fence reads
#define CHEB_WAIT(N)                                      \
  do {                                                    \
    asm volatile("s_waitcnt vmcnt(" #N ")" ::: "memory"); \
    __builtin_amdgcn_s_barrier();                         \
    asm volatile("" ::: "memory");                        \
  } while (0)

// ---------------- pack kernels ----------------

// 64x64 f32 tiles: bf16 S_z (row-major) + bf16 S_z^T (for sq_gemm A operand).
__global__ __launch_bounds__(256) void pack_supports(
    const float* __restrict__ s0, const float* __restrict__ s1,
    u16* __restrict__ d0, u16* __restrict__ d1,
    u16* __restrict__ t0, u16* __restrict__ t1) {
  __shared__ float tile[64][65];
  const int z = blockIdx.y;
  const float* S = z ? s1 : s0;
  u16* D = z ? d1 : d0;
  u16* T = z ? t1 : t0;
  const int r0 = (blockIdx.x >> 4) * 64, c0 = (blockIdx.x & 15) * 64;
  const int t = threadIdx.x;
  int cc4 = (t & 15) * 4, rr = t >> 4;
#pragma unroll
  for (int p = 0; p < 4; p++) {
    int r = p * 16 + rr;
    f32x4 v = *(const f32x4*)(S + (size_t)(r0 + r) * NN + c0 + cc4);
    tile[r][cc4] = v.x; tile[r][cc4 + 1] = v.y;
    tile[r][cc4 + 2] = v.z; tile[r][cc4 + 3] = v.w;
    u16x4 o;
    o.x = f2bf(v.x); o.y = f2bf(v.y); o.z = f2bf(v.z); o.w = f2bf(v.w);
    *(u16x4*)&D[(size_t)(r0 + r) * NN + c0 + cc4] = o;
  }
  __syncthreads();
  int rr4 = (t & 15) * 4, cc = t >> 4;
#pragma unroll
  for (int p = 0; p < 4; p++) {
    int c = p * 16 + cc;
    u16x4 o;
    o.x = f2bf(tile[rr4][c]);     o.y = f2bf(tile[rr4 + 1][c]);
    o.z = f2bf(tile[rr4 + 2][c]); o.w = f2bf(tile[rr4 + 3][c]);
    *(u16x4*)&T[(size_t)(c0 + c) * NN + r0 + rr4] = o;
  }
}

// Fragment-ordered W with Chebyshev fold:
//   slot m=0: W0 - W2 - W4 ; m=2: 2*W2 ; m=4: 2*W4 ; m=1,3 unchanged.
// WF[(c*nj+j)*64 + lane][e]: kp = c*32 + (lane>>4)*8 + e, o = j*16+(lane&15).
__global__ __launch_bounds__(64) void pack_wf(
    const float* __restrict__ Wo, const float* __restrict__ Wu,
    u16* __restrict__ WF1, u16* __restrict__ WF2) {
  const int c = blockIdx.x;   // 0..10
  int j = blockIdx.y;         // 0..11
  const float* W; u16* WF; int ldo, nj;
  if (j < 8) { W = Wo; WF = WF1; ldo = 128; nj = 8; }
  else       { j -= 8; W = Wu; WF = WF2; ldo = 64; nj = 4; }
  const int lane = threadIdx.x;
  const int o = j * 16 + (lane & 15);
  const int kpb = c * 32 + (lane >> 4) * 8;
  u16 vals[8];
#pragma unroll
  for (int e = 0; e < 8; e++) {
    const int kp = kpb + e;
    float v = 0.f;
    if (kp < 330) {
      const int m = kp / 66;
      const int f = kp - m * 66;
      const float* Wrow = W + (size_t)(f * 5) * ldo + o;
      if (m == 0)      v = Wrow[0] - Wrow[2 * ldo] - Wrow[4 * ldo];
      else if (m == 2) v = 2.f * Wrow[2 * ldo];
      else if (m == 4) v = 2.f * Wrow[4 * ldo];
      else             v = Wrow[(size_t)m * ldo];
    }
    vals[e] = f2bf(v);
  }
  u16* dst = WF + (((size_t)(c * nj + j) << 6) + lane) * 8;
#pragma unroll
  for (int e = 0; e < 8; e++) dst[e] = vals[e];
}

// X0^T rows: f=0,1 from inputs (threads 0..31) + f>=2 from hx (64x64 LDS
// transpose tiles, all 256 threads). Block (node-tile, b).
__global__ __launch_bounds__(256) void pack_x0(
    const float* __restrict__ inp, const float* __restrict__ hx,
    u16* __restrict__ x0t, u16* __restrict__ x0pt) {
  __shared__ float tile[64][65];
  int n0 = blockIdx.x * 64, b = blockIdx.y, t = threadIdx.x;
  if (t < 32) {  // f=0,1: x0t[f*64+b][n] = inputs[b][2n+f]
    const int f = t >> 4;
    const int n4 = (t & 15) * 4;
    const float* src = inp + b * 2048 + (n0 + n4) * 2 + f;
    u16x4 o;
    o.x = f2bf(src[0]); o.y = f2bf(src[2]); o.z = f2bf(src[4]); o.w = f2bf(src[6]);
    size_t off = (size_t)(f * 64 + b) * NN + n0 + n4;
    *(u16x4*)(x0t + off) = o;
    *(u16x4*)(x0pt + off) = o;
  }
  int u4 = (t & 15) * 4, r0 = t >> 4;
#pragma unroll
  for (int p = 0; p < 4; p++) {
    int row = p * 16 + r0;
    f32x4 v = *(const f32x4*)(hx + ((size_t)b << 16) + (size_t)(n0 + row) * 64 + u4);
    tile[row][u4] = v.x; tile[row][u4 + 1] = v.y;
    tile[row][u4 + 2] = v.z; tile[row][u4 + 3] = v.w;
  }
  __syncthreads();
  int n4 = (t & 15) * 4, uu0 = t >> 4;
#pragma unroll
  for (int p = 0; p < 4; p++) {
    int u = p * 16 + uu0;
    u16x4 o;
    o.x = f2bf(tile[n4][u]);     o.y = f2bf(tile[n4 + 1][u]);
    o.z = f2bf(tile[n4 + 2][u]); o.w = f2bf(tile[n4 + 3][u]);
    *(u16x4*)&x0t[(size_t)((2 + u) * 64 + b) * NN + n0 + n4] = o;
  }
}

// SS_z = S_z @ S_z via A = ST_z, Xi = S_z: C[m][col] = sum_k S[k][m] S[col][k]
// = SS[col][m], stored Xo[col][m] -> SS row-major.
// BK=64 DOUBLE-buffered deep pipeline (64KB LDS): at 0.5 blocks/CU the wall
// time is one block's serial latency -> 16 K-steps, stage t+2 issued right
// after compute t (counted vmcnt(8); 0 only at tail). LDS row = 8 chunks of
// 16B; phys chunk = logical ^ (row&7); staging key (lane&7)^(lane>>3).
__global__ __launch_bounds__(256) void sq_gemm(
    const u16* __restrict__ S0, const u16* __restrict__ S1,
    const u16* __restrict__ ST0, const u16* __restrict__ ST1,
    u16* __restrict__ SS0, u16* __restrict__ SS1) {
  __shared__ u16 As[2][128 * 64];
  __shared__ u16 Bs[2][128 * 64];
  const int t = threadIdx.x;
  const int lane = t & 63;
  const int w = t >> 6;
  const int lid = blockIdx.x;                  // 128 blocks
  const int work = (lid & 7) * 16 + (lid >> 3);
  const int z = work >> 6;
  const int rr = work & 63;
  const int y = rr >> 3, x = rr & 7;
  const u16* A = z ? ST1 : ST0;
  const u16* Xi = z ? S1 : S0;
  u16* Xo = z ? SS1 : SS0;
  const int m0 = y * 128, n0 = x * 128;

  const int swz = ((lane & 7) ^ (lane >> 3)) * 8;  // u16 offset in 64-elem row
  const int rl = lane >> 3;
  const int rA = m0 + w * 32 + rl;
  const int rB = n0 + w * 32 + rl;
  const int dW = (w * 32) * 64;  // wave-uniform LDS u16 offset

  const int wm = (w >> 1) * 64;
  const int wn = (w & 1) * 64;
  const int fr = lane & 15;
  const int q = lane >> 4;

  f32x4 acc[4][4];
#pragma unroll
  for (int i = 0; i < 4; i++)
#pragma unroll
    for (int j = 0; j < 4; j++) acc[i][j] = f32x4{0.f, 0.f, 0.f, 0.f};

  auto stage = [&](int buf, int k0) {
    u16* a = &As[buf][0] + dW;
    u16* b = &Bs[buf][0] + dW;
#pragma unroll
    for (int g = 0; g < 4; g++) {
      gload16(A + (size_t)(rA + g * 8) * NN + k0 + swz, a + g * 8 * 64);
      gload16(Xi + (size_t)(rB + g * 8) * NN + k0 + swz, b + g * 8 * 64);
    }
  };
  auto compute = [&](int buf) {
    const u16* a = &As[buf][0];
    const u16* b = &Bs[buf][0];
#pragma unroll
    for (int kk = 0; kk < 2; kk++) {
      const int fo = ((kk * 4 + q) ^ (fr & 7)) * 8;  // phys chunk un-swizzle
      s16x8 af[4], bfr[4];
#pragma unroll
      for (int i = 0; i < 4; i++)
        af[i] = *(const s16x8*)&a[(wm + i * 16 + fr) * 64 + fo];
#pragma unroll
      for (int j = 0; j < 4; j++)
        bfr[j] = *(const s16x8*)&b[(wn + j * 16 + fr) * 64 + fo];
#pragma unroll
      for (int i = 0; i < 4; i++)
#pragma unroll
        for (int j = 0; j < 4; j++)
          acc[i][j] = __builtin_amdgcn_mfma_f32_16x16x32_bf16(af[i], bfr[j], acc[i][j], 0, 0, 0);
    }
  };

  stage(0, 0);
  stage(1, 64);
#pragma unroll 1
  for (int tI = 0; tI < 14; tI++) {
    CHEB_WAIT(8);                       // tile tI landed (tI+1 in flight)
    compute(tI & 1);
    __builtin_amdgcn_s_barrier();       // readers done before overwrite
    stage(tI & 1, (tI + 2) * 64);
  }
  CHEB_WAIT(8); compute(0);             // tI=14
  CHEB_WAIT(0); compute(1);             // tI=15

  const int nr0 = (lane >> 4) << 2;
#pragma unroll
  for (int i = 0; i < 4; i++) {
    const int node = m0 + wm + i * 16 + nr0;
#pragma unroll
    for (int j = 0; j < 4; j++) {
      const int colg = n0 + wn + j * 16 + fr;
      f32x4 c = acc[i][j];
      u16x4 o;
      o.x = f2bf(c.x); o.y = f2bf(c.y); o.z = f2bf(c.z); o.w = f2bf(c.w);
      *(u16x4*)&Xo[(size_t)colg * NN + node] = o;
    }
  }
}

// ---------------- gconv GEMM: 256x128 tile, 512 threads, 8 waves ----------------
// C[m][col] = A[m][:] . Xi[col][:],  write Xo[col][m] (bf16).
// Waves 4M x 2N; wave w owns quadrant rows (w>>1)*64, cols (w&1)*64 -> the
// SAME 64x64 acc[4][4] math as the verified 128x128 core. Staging per wave:
// A rows [w*32,w*32+32) (2 gloads x 16 rows), B rows [w*16,w*16+16)
// (1 gload). 3 LDS buffers (72KB), counted vmcnt(3).
// 528 blocks = 16 mt x 33 nt, XCD-bijective (528%8==0):
//   matrix = mt>>2 (S0,SS0,S1,SS1 order via table), m0 = (mt&3)*256.
__global__ __launch_bounds__(512, 2) void gconv_gemm(
    const u16* __restrict__ S0, const u16* __restrict__ S1,
    const u16* __restrict__ SS0, const u16* __restrict__ SS1,
    const u16* __restrict__ Xi,
    u16* __restrict__ X1, u16* __restrict__ X2,
    u16* __restrict__ X3, u16* __restrict__ X4) {
  __shared__ u16 As[3][256 * 32];
  __shared__ u16 Bs[3][128 * 32];
  const int t = threadIdx.x;
  const int lane = t & 63;
  const int w = t >> 6;  // 0..7

  const int lid = blockIdx.x;
  const int work = (lid & 7) * 66 + (lid >> 3);
  const int mt = work / 33;   // 0..15
  const int nt = work % 33;   // 0..32
  const int md = mt >> 2;     // which matrix
  const u16* A = md == 0 ? S0 : md == 1 ? SS0 : md == 2 ? S1 : SS1;
  u16* Xo = md == 0 ? X1 : md == 1 ? X2 : md == 2 ? X3 : X4;
  const int m0 = (mt & 3) * 256;
  const int n0 = nt * 128;

  // staging (same swizzle relation as verified core: key = (row>>1)&3)
  const int swz = ((lane & 3) ^ ((lane >> 3) & 3)) * 8;  // u16 offset in row
  const int rl = lane >> 2;   // 0..15
  const u16* pA0 = A + (size_t)(m0 + w * 32 + rl) * NN + swz;
  const u16* pA1 = pA0 + (size_t)16 * NN;
  const u16* pB0 = Xi + (size_t)(n0 + w * 16 + rl) * NN + swz;
  const int dA0 = (w * 32) * 32;        // LDS u16 offsets, wave-uniform
  const int dA1 = (w * 32 + 16) * 32;
  const int dB = (w * 16) * 32;

  const int wm = (w >> 1) * 64;   // 0..192
  const int wn = (w & 1) * 64;    // 0 or 64
  const int fr = lane & 15;
  const int q = lane >> 4;
  const int fo = (q ^ ((fr >> 1) & 3)) * 8;  // frag chunk un-swizzle

  f32x4 acc[4][4];
#pragma unroll
  for (int i = 0; i < 4; i++)
#pragma unroll
    for (int j = 0; j < 4; j++) acc[i][j] = f32x4{0.f, 0.f, 0.f, 0.f};

  auto stage = [&](u16* dAp, u16* dBp) {
    gload16(pA0, dAp + dA0);
    gload16(pA1, dAp + dA1);
    gload16(pB0, dBp + dB);
    pA0 += 32; pA1 += 32; pB0 += 32;
  };
  auto compute = [&](const u16* cA, const u16* cB) {
    s16x8 af[4], bfr[4];
#pragma unroll
    for (int i = 0; i < 4; i++)
      af[i] = *(const s16x8*)&cA[(wm + i * 16 + fr) * 32 + fo];
#pragma unroll
    for (int j = 0; j < 4; j++)
      bfr[j] = *(const s16x8*)&cB[(wn + j * 16 + fr) * 32 + fo];
#pragma unroll
    for (int i = 0; i < 4; i++)
#pragma unroll
      for (int j = 0; j < 4; j++)
        acc[i][j] = __builtin_amdgcn_mfma_f32_16x16x32_bf16(af[i], bfr[j], acc[i][j], 0, 0, 0);
  };

  u16* a0 = &As[0][0]; u16* a1 = &As[1][0]; u16* a2 = &As[2][0];
  u16* b0 = &Bs[0][0]; u16* b1 = &Bs[1][0]; u16* b2 = &Bs[2][0];

  // pipeline: stage t=0,1; steady state keeps 6 loads in flight, waits only
  // for the 2-iteration-old tile (vmcnt(3)); vmcnt(0) only at the last step.
  stage(a0, b0);
  stage(a1, b1);
#pragma unroll 1
  for (int it = 0; it < 10; it++) {  // t = 3*it + {0,1,2}, t in [0,30)
    CHEB_WAIT(3); stage(a2, b2); compute(a0, b0);
    CHEB_WAIT(3); stage(a0, b0); compute(a1, b1);
    CHEB_WAIT(3); stage(a1, b1); compute(a2, b2);
  }
  CHEB_WAIT(3); compute(a0, b0);  // t=30
  CHEB_WAIT(0); compute(a1, b1);  // t=31

  // C/D layout: col = lane&15, row = (lane>>4)*4 + reg
  const int nr0 = (lane >> 4) << 2;
#pragma unroll
  for (int i = 0; i < 4; i++) {
    const int node = m0 + wm + i * 16 + nr0;
#pragma unroll
    for (int j = 0; j < 4; j++) {
      const int colg = n0 + wn + j * 16 + fr;
      f32x4 c = acc[i][j];
      u16x4 o;
      o.x = f2bf(c.x); o.y = f2bf(c.y); o.z = f2bf(c.z); o.w = f2bf(c.w);
      *(u16x4*)&Xo[(size_t)colg * NN + node] = o;
    }
  }
}

// ---------------- projections (MFMA) ----------------
// A-LDS [64 n][ASTRIDE kp]: staged via 4x4 register-transpose blocks.
// BURST: all global loads (6 iters x 4 rows) issued into registers first,
// then all LDS writes -> one latency wait instead of six.

__device__ __forceinline__ void proj_stage(
    u16* A, const u16* __restrict__ X0, const u16* __restrict__ X1,
    const u16* __restrict__ X2, const u16* __restrict__ X3,
    const u16* __restrict__ X4, int b, int n0, int t) {
  u16x4 v[6][4];
#pragma unroll
  for (int i = 0; i < 6; i++) {  // 88 kp4-groups x 16 n4-groups = 1408 ids
    const int idx = t + i * 256;
    if (idx < 1408) {
      const int kp0 = (idx >> 4) * 4;
      const int n4 = (idx & 15) * 4;
#pragma unroll
      for (int r = 0; r < 4; r++) {
        const int kp = kp0 + r;
        if (kp < 330) {
          const int m = kp / 66;
          const int f = kp - m * 66;
          const u16* Xm = m == 0 ? X0 : m == 1 ? X1 : m == 2 ? X2 : m == 3 ? X3 : X4;
          v[i][r] = *(const u16x4*)(Xm + (size_t)(f * 64 + b) * NN + n0 + n4);
        } else {
          v[i][r] = u16x4{0, 0, 0, 0};
        }
      }
    }
  }
#pragma unroll
  for (int i = 0; i < 6; i++) {
    const int idx = t + i * 256;
    if (idx < 1408) {
      const int kp0 = (idx >> 4) * 4;
      const int n4 = (idx & 15) * 4;
#pragma unroll
      for (int c = 0; c < 4; c++) {
        u16x4 o;
        o.x = v[i][0][c]; o.y = v[i][1][c]; o.z = v[i][2][c]; o.w = v[i][3][c];
        *(u16x4*)&A[(n4 + c) * ASTRIDE + kp0] = o;
      }
    }
  }
}

// gconv1 projection: [64n x 330] @ W1 -> 128 outs; sigmoid; r*hx -> X0'^T; u -> uout.
// Wave split: wave w covers rows (w>>1)*32..+32, outputs half jh=w&1
// (jh=0: o 0..63 r-part; jh=1: o 64..127 u-part) -> wave-uniform epilogue.
__global__ __launch_bounds__(256) void proj1(
    const u16* __restrict__ X0, const u16* __restrict__ X1, const u16* __restrict__ X2,
    const u16* __restrict__ X3, const u16* __restrict__ X4,
    const u16* __restrict__ WF, const float* __restrict__ bias,
    const float* __restrict__ hx, u16* __restrict__ X0p, float* __restrict__ uout) {
  __shared__ u16 A[64 * ASTRIDE];
  const int t = threadIdx.x;
  const int n0 = blockIdx.x * 64;
  const int b = blockIdx.y;
  proj_stage(A, X0, X1, X2, X3, X4, b, n0, t);
  __syncthreads();

  const int lane = t & 63;
  const int w = t >> 6;
  const int fr = lane & 15;
  const int q8 = (lane >> 4) * 8;
  const int nb = (w >> 1) * 32;
  const int jh = w & 1;
  const u16* arow = &A[(nb + fr) * ASTRIDE + q8];
  const u16* wfl = WF + (size_t)lane * 8;  // + (c*8 + jh*4 + j)*512

  f32x4 acc[2][4];
#pragma unroll
  for (int ii = 0; ii < 2; ii++)
#pragma unroll
    for (int j = 0; j < 4; j++) acc[ii][j] = f32x4{0.f, 0.f, 0.f, 0.f};

  for (int c = 0; c < 11; c++) {
    s16x8 af[2];
#pragma unroll
    for (int ii = 0; ii < 2; ii++)
      af[ii] = *(const s16x8*)(arow + ii * 16 * ASTRIDE + c * 32);
#pragma unroll
    for (int j = 0; j < 4; j++) {
      const s16x8 bf = *(const s16x8*)(wfl + ((c * 8 + jh * 4 + j) << 9));
#pragma unroll
      for (int ii = 0; ii < 2; ii++)
        acc[ii][j] = __builtin_amdgcn_mfma_f32_16x16x32_bf16(af[ii], bf, acc[ii][j], 0, 0, 0);
    }
  }

  // D layout: col(o within sub) = lane&15, row(n within sub) = (lane>>4)*4 + reg
  const int nl0 = (lane >> 4) * 4;
#pragma unroll
  for (int ii = 0; ii < 2; ii++) {
    const int n = n0 + nb + ii * 16 + nl0;  // + reg
#pragma unroll
    for (int j = 0; j < 4; j++) {
      const int ol = j * 16 + fr;           // o within half
      const float bs = bias[jh * 64 + ol];
      f32x4 v;
      v.x = 1.f / (1.f + __expf(-(acc[ii][j].x + bs)));
      v.y = 1.f / (1.f + __expf(-(acc[ii][j].y + bs)));
      v.z = 1.f / (1.f + __expf(-(acc[ii][j].z + bs)));
      v.w = 1.f / (1.f + __expf(-(acc[ii][j].w + bs)));
      if (jh == 0) {  // r-part -> X0'^T row (2+ol)*64+b, times hx
        const float* hxp = hx + ((size_t)b << 16) + (size_t)n * 64 + ol;
        u16x4 s;
        s.x = f2bf(v.x * hxp[0 * 64]);
        s.y = f2bf(v.y * hxp[1 * 64]);
        s.z = f2bf(v.z * hxp[2 * 64]);
        s.w = f2bf(v.w * hxp[3 * 64]);
        *(u16x4*)&X0p[(size_t)((2 + ol) * 64 + b) * NN + n] = s;
      } else {  // u-part -> uout (d_out scratch)
        float* up = uout + (((size_t)b << 10) + n) * 64 + ol;
        up[0 * 64] = v.x; up[1 * 64] = v.y; up[2 * 64] = v.z; up[3 * 64] = v.w;
      }
    }
  }
}

// gconv2 projection: tanh + GRU blend. uin aliases out (same layout) - no restrict.
// Wave split: rows (w>>1)*32..+32, output half jh=w&1 (o = jh*32 + j*16 + fr).
__global__ __launch_bounds__(256) void proj2(
    const u16* __restrict__ X0, const u16* __restrict__ X1, const u16* __restrict__ X2,
    const u16* __restrict__ X3, const u16* __restrict__ X4,
    const u16* __restrict__ WF, const float* __restrict__ bias,
    const float* __restrict__ hx, const float* uin, float* out) {
  __shared__ u16 A[64 * ASTRIDE];
  const int t = threadIdx.x;
  const int n0 = blockIdx.x * 64;
  const int b = blockIdx.y;
  proj_stage(A, X0, X1, X2, X3, X4, b, n0, t);
  __syncthreads();

  const int lane = t & 63;
  const int w = t >> 6;
  const int fr = lane & 15;
  const int q8 = (lane >> 4) * 8;
  const int nb = (w >> 1) * 32;
  const int jh = w & 1;
  const u16* arow = &A[(nb + fr) * ASTRIDE + q8];
  const u16* wfl = WF + (size_t)lane * 8;  // + (c*4 + jh*2 + j)*512

  f32x4 acc[2][2];
#pragma unroll
  for (int ii = 0; ii < 2; ii++)
#pragma unroll
    for (int j = 0; j < 2; j++) acc[ii][j] = f32x4{0.f, 0.f, 0.f, 0.f};

  for (int c = 0; c < 11; c++) {
    s16x8 af[2];
#pragma unroll
    for (int ii = 0; ii < 2; ii++)
      af[ii] = *(const s16x8*)(arow + ii * 16 * ASTRIDE + c * 32);
#pragma unroll
    for (int j = 0; j < 2; j++) {
      const s16x8 bf = *(const s16x8*)(wfl + ((c * 4 + jh * 2 + j) << 9));
#pragma unroll
      for (int ii = 0; ii < 2; ii++)
        acc[ii][j] = __builtin_amdgcn_mfma_f32_16x16x32_bf16(af[ii], bf, acc[ii][j], 0, 0, 0);
    }
  }

  const int nl0 = (lane >> 4) * 4;
#pragma unroll
  for (int ii = 0; ii < 2; ii++) {
    const int n = n0 + nb + ii * 16 + nl0;  // + reg
#pragma unroll
    for (int j = 0; j < 2; j++) {
      const int o = jh * 32 + j * 16 + fr;
      const float bs = bias[o];
      const size_t base = (((size_t)b << 10) + n) * 64 + o;  // + reg*64
      float c0 = tanhf(acc[ii][j].x + bs);
      float c1 = tanhf(acc[ii][j].y + bs);
      float c2 = tanhf(acc[ii][j].z + bs);
      float c3 = tanhf(acc[ii][j].w + bs);
      float u0 = uin[base + 0 * 64], u1 = uin[base + 1 * 64];
      float u2 = uin[base + 2 * 64], u3 = uin[base + 3 * 64];
      float h0 = hx[base + 0 * 64], h1 = hx[base + 1 * 64];
      float h2 = hx[base + 2 * 64], h3 = hx[base + 3 * 64];
      out[base + 0 * 64] = u0 * h0 + (1.f - u0) * c0;
      out[base + 1 * 64] = u1 * h1 + (1.f - u1) * c1;
      out[base + 2 * 64] = u2 * h2 + (1.f - u2) * c2;
      out[base + 3 * 64] = u3 * h3 + (1.f - u3) * c3;
    }
  }
}

// ---------------- launch ----------------

extern "C" void kernel_launch(void* const* d_in, const int* in_sizes, int n_in,
                              void* d_out, int out_size, void* d_ws, size_t ws_size,
                              hipStream_t stream) {
  (void)in_sizes; (void)n_in; (void)out_size; (void)ws_size;
  const float* inp = (const float*)d_in[0];
  const float* hx  = (const float*)d_in[1];
  const float* s0  = (const float*)d_in[2];
  const float* s1  = (const float*)d_in[3];
  const float* Wo  = (const float*)d_in[4];
  const float* bo  = (const float*)d_in[5];
  const float* Wu  = (const float*)d_in[6];
  const float* bu  = (const float*)d_in[7];
  float* out = (float*)d_out;

  char* p = (char*)d_ws;
  u16* Sb0 = (u16*)p; p += (size_t)NN * NN * 2;
  u16* Sb1 = (u16*)p; p += (size_t)NN * NN * 2;
  u16* SSb0 = (u16*)p; p += (size_t)NN * NN * 2;
  u16* SSb1 = (u16*)p; p += (size_t)NN * NN * 2;
  const size_t xbytes = (size_t)NCOLS * NN * 2;
  u16* X0T = (u16*)p; p += xbytes;
  u16* X1T = (u16*)p; p += xbytes;
  u16* X2T = (u16*)p; p += xbytes;
  u16* X3T = (u16*)p; p += xbytes;
  u16* X4T = (u16*)p; p += xbytes;
  u16* X0P = (u16*)p; p += xbytes;
  u16* WF1 = (u16*)p; p += (size_t)11 * 8 * 512 * 2;  // 90112 B
  u16* WF2 = (u16*)p; p += (size_t)11 * 4 * 512 * 2;  // 45056 B
  // ST scratch: X1T/X3T are not written until gconv1, free for sq_gemm input.
  u16* ST0 = X1T;
  u16* ST1 = X3T;
  // total ws use: 8 MB + 6*8.25 MB + ~132 KB

  pack_supports<<<dim3(256, 2), dim3(256), 0, stream>>>(s0, s1, Sb0, Sb1, ST0, ST1);
  sq_gemm<<<dim3(128), dim3(256), 0, stream>>>(Sb0, Sb1, ST0, ST1, SSb0, SSb1);
  pack_wf<<<dim3(11, 12), dim3(64), 0, stream>>>(Wo, Wu, WF1, WF2);
  pack_x0<<<dim3(16, 64), dim3(256), 0, stream>>>(inp, hx, X0T, X0P);
  // gconv1: X1=S0 X0, X3=S1 X0, Y2=SS0 X0, Y4=SS1 X0 (one launch; fold in WF)
  gconv_gemm<<<dim3(528), dim3(512), 0, stream>>>(Sb0, Sb1, SSb0, SSb1, X0T,
                                                  X1T, X2T, X3T, X4T);
  proj1<<<dim3(16, 64), dim3(256), 0, stream>>>(X0T, X1T, X2T, X3T, X4T, WF1, bo, hx, X0P, out);
  // gconv2 on X0'
  gconv_gemm<<<dim3(528), dim3(512), 0, stream>>>(Sb0, Sb1, SSb0, SSb1, X0P,
                                                  X1T, X2T, X3T, X4T);
  proj2<<<dim3(16, 64), dim3(256), 0, stream>>>(X0P, X1T, X2T, X3T, X4T, WF2, bu, hx, out, out);
}

// Round 12
// 261.454 us; speedup vs baseline: 1.0385x; 1.0385x over previous
//
#include <hip/hip_runtime.h>

// DCGRU cell, MI355X.  (Consolidation: R10 gconv/sq + 2-phase 6/CU proj + merged packs.)
//   Diffusion intermediates TRANSPOSED: XT[col = f*64+b][node n] in bf16.
//   pack_all (one launch): supports->bf16+transpose | X0^T build | WF fold.
//   sq_gemm (once): SS_z = S_z @ S_z, BK=64 double-buffered deep pipe.
//   gconv_gemm: 1056 blocks = two 528-halves of verified 128x128 decode;
//     BK=32, TRIPLE-buffered LDS, counted vmcnt(4). XOR swizzle via
//     pre-swizzled GLOBAL source. Chebyshev "2Y-X0" folded into W.
//   proj1/proj2: TWO-PHASE K staging into A[64][200] (25.6KB -> 6 blocks/CU,
//     all 1024 blocks resident -> no round tail; 200 u16 = 25 x 16B units,
//     25=1 mod 8 -> conflict-free ds_read_b128 A-frags; write stride
//     100dw=4 mod 32 -> 2-way free). Burst staging per phase. Wave split:
//     32 n-rows x half the o-outputs. WF in fragment order (coalesced).
//   d_out doubles as u-buffer.

typedef unsigned short u16;
typedef unsigned int u32;
typedef short s16x8 __attribute__((ext_vector_type(8)));
typedef float f32x4 __attribute__((ext_vector_type(4)));
typedef u16 u16x4 __attribute__((ext_vector_type(4)));

#define NN 1024
#define NB 64
#define NF 66
#define NCOLS 4224  // NF*NB
#define KPAD 352    // 330 padded to 11*32
#define PSTRIDE 200 // proj A-LDS row stride in u16 (400B = 25x16B, odd units)

__device__ __forceinline__ u16 f2bf(float f) {
  u32 u = __builtin_bit_cast(u32, f);
  u = (u + 0x7fffu + ((u >> 16) & 1u)) >> 16;  // RNE
  return (u16)u;
}
__device__ __forceinline__ float bf2f(u16 h) {
  u32 u = ((u32)h) << 16;
  return __builtin_bit_cast(float, u);
}

__device__ __forceinline__ void gload16(const void* g, void* l) {
  __builtin_amdgcn_global_load_lds(
      (const __attribute__((address_space(1))) u32*)g,
      (__attribute__((address_space(3))) u32*)l, 16, 0, 0);
}

// counted-vmcnt barrier: own oldest loads landed -> barrier -> fence reads
#define CHEB_WAIT(N)                                      \
  do {                                                    \
    asm volatile("s_waitcnt vmcnt(" #N ")" ::: "memory"); \
    __builtin_amdgcn_s_barrier();                         \
    asm volatile("" ::: "memory");                        \
  } while (0)

// ---------------- merged pack kernel ----------------
// blocks [0,512): supports (z = bid>>8, tile = bid&255): bf16 S_z row-major
//   into Sb_z + bf16 S_z^T into ST_z.
// blocks [512,1536): X0^T build (idx = bid-512: n-tile = idx&15, b = idx>>4).
// blocks [1536,1569): WF fold: gid=(bid-1536)*256+t; pair=gid>>6 (0..131);
//   lane=gid&63; c=pair%11; jj=pair/11 (jj<8 -> Wo/WF1, else Wu/WF2).
__global__ __launch_bounds__(256) void pack_all(
    const float* __restrict__ s0, const float* __restrict__ s1,
    const float* __restrict__ inp, const float* __restrict__ hx,
    const float* __restrict__ Wo, const float* __restrict__ Wu,
    u16* __restrict__ Sb0, u16* __restrict__ Sb1,
    u16* __restrict__ ST0, u16* __restrict__ ST1,
    u16* __restrict__ x0t, u16* __restrict__ x0pt,
    u16* __restrict__ WF1, u16* __restrict__ WF2) {
  __shared__ float tile[64][65];
  const int bid = blockIdx.x;
  const int t = threadIdx.x;

  if (bid < 512) {  // ---- supports ----
    const int z = bid >> 8;
    const int bx = bid & 255;
    const float* S = z ? s1 : s0;
    u16* D = z ? Sb1 : Sb0;
    u16* T = z ? ST1 : ST0;
    const int r0 = (bx >> 4) * 64, c0 = (bx & 15) * 64;
    int cc4 = (t & 15) * 4, rr = t >> 4;
#pragma unroll
    for (int p = 0; p < 4; p++) {
      int r = p * 16 + rr;
      f32x4 v = *(const f32x4*)(S + (size_t)(r0 + r) * NN + c0 + cc4);
      tile[r][cc4] = v.x; tile[r][cc4 + 1] = v.y;
      tile[r][cc4 + 2] = v.z; tile[r][cc4 + 3] = v.w;
      u16x4 o;
      o.x = f2bf(v.x); o.y = f2bf(v.y); o.z = f2bf(v.z); o.w = f2bf(v.w);
      *(u16x4*)&D[(size_t)(r0 + r) * NN + c0 + cc4] = o;
    }
    __syncthreads();
    int rr4 = (t & 15) * 4, cc = t >> 4;
#pragma unroll
    for (int p = 0; p < 4; p++) {
      int c = p * 16 + cc;
      u16x4 o;
      o.x = f2bf(tile[rr4][c]);     o.y = f2bf(tile[rr4 + 1][c]);
      o.z = f2bf(tile[rr4 + 2][c]); o.w = f2bf(tile[rr4 + 3][c]);
      *(u16x4*)&T[(size_t)(c0 + c) * NN + r0 + rr4] = o;
    }
  } else if (bid < 1536) {  // ---- X0^T ----
    const int idx = bid - 512;
    const int n0 = (idx & 15) * 64, b = idx >> 4;
    if (t < 32) {  // f=0,1: x0t[f*64+b][n] = inputs[b][2n+f]
      const int f = t >> 4;
      const int n4 = (t & 15) * 4;
      const float* src = inp + b * 2048 + (n0 + n4) * 2 + f;
      u16x4 o;
      o.x = f2bf(src[0]); o.y = f2bf(src[2]); o.z = f2bf(src[4]); o.w = f2bf(src[6]);
      size_t off = (size_t)(f * 64 + b) * NN + n0 + n4;
      *(u16x4*)(x0t + off) = o;
      *(u16x4*)(x0pt + off) = o;
    }
    int u4 = (t & 15) * 4, r0 = t >> 4;
#pragma unroll
    for (int p = 0; p < 4; p++) {
      int row = p * 16 + r0;
      f32x4 v = *(const f32x4*)(hx + ((size_t)b << 16) + (size_t)(n0 + row) * 64 + u4);
      tile[row][u4] = v.x; tile[row][u4 + 1] = v.y;
      tile[row][u4 + 2] = v.z; tile[row][u4 + 3] = v.w;
    }
    __syncthreads();
    int n4 = (t & 15) * 4, uu0 = t >> 4;
#pragma unroll
    for (int p = 0; p < 4; p++) {
      int u = p * 16 + uu0;
      u16x4 o;
      o.x = f2bf(tile[n4][u]);     o.y = f2bf(tile[n4 + 1][u]);
      o.z = f2bf(tile[n4 + 2][u]); o.w = f2bf(tile[n4 + 3][u]);
      *(u16x4*)&x0t[(size_t)((2 + u) * 64 + b) * NN + n0 + n4] = o;
    }
  } else {  // ---- WF fold ----
    const int gid = (bid - 1536) * 256 + t;
    const int pair = gid >> 6;   // 0..131
    const int lane = gid & 63;
    const int c = pair % 11;
    int jj = pair / 11;          // 0..11
    const float* W; u16* WF; int ldo, nj;
    if (jj < 8) { W = Wo; WF = WF1; ldo = 128; nj = 8; }
    else        { jj -= 8; W = Wu; WF = WF2; ldo = 64; nj = 4; }
    const int o = jj * 16 + (lane & 15);
    const int kpb = c * 32 + (lane >> 4) * 8;
    u16 vals[8];
#pragma unroll
    for (int e = 0; e < 8; e++) {
      const int kp = kpb + e;
      float v = 0.f;
      if (kp < 330) {
        const int m = kp / 66;
        const int f = kp - m * 66;
        const float* Wrow = W + (size_t)(f * 5) * ldo + o;
        if (m == 0)      v = Wrow[0] - Wrow[2 * ldo] - Wrow[4 * ldo];
        else if (m == 2) v = 2.f * Wrow[2 * ldo];
        else if (m == 4) v = 2.f * Wrow[4 * ldo];
        else             v = Wrow[(size_t)m * ldo];
      }
      vals[e] = f2bf(v);
    }
    u16* dst = WF + (((size_t)(c * nj + jj) << 6) + lane) * 8;
#pragma unroll
    for (int e = 0; e < 8; e++) dst[e] = vals[e];
  }
}

// SS_z = S_z @ S_z via A = ST_z, Xi = S_z: C[m][col] = sum_k S[k][m] S[col][k]
// = SS[col][m], stored Xo[col][m] -> SS row-major.
// BK=64 DOUBLE-buffered deep pipeline (64KB LDS): at 0.5 blocks/CU the wall
// time is one block's serial latency -> 16 K-steps, stage t+2 issued right
// after compute t (counted vmcnt(8); 0 only at tail). LDS row = 8 chunks of
// 16B; phys chunk = logical ^ (row&7); staging key (lane&7)^(lane>>3).
__global__ __launch_bounds__(256) void sq_gemm(
    const u16* __restrict__ S0, const u16* __restrict__ S1,
    const u16* __restrict__ ST0, const u16* __restrict__ ST1,
    u16* __restrict__ SS0, u16* __restrict__ SS1) {
  __shared__ u16 As[2][128 * 64];
  __shared__ u16 Bs[2][128 * 64];
  const int t = threadIdx.x;
  const int lane = t & 63;
  const int w = t >> 6;
  const int lid = blockIdx.x;                  // 128 blocks
  const int work = (lid & 7) * 16 + (lid >> 3);
  const int z = work >> 6;
  const int rr = work & 63;
  const int y = rr >> 3, x = rr & 7;
  const u16* A = z ? ST1 : ST0;
  const u16* Xi = z ? S1 : S0;
  u16* Xo = z ? SS1 : SS0;
  const int m0 = y * 128, n0 = x * 128;

  const int swz = ((lane & 7) ^ (lane >> 3)) * 8;  // u16 offset in 64-elem row
  const int rl = lane >> 3;
  const int rA = m0 + w * 32 + rl;
  const int rB = n0 + w * 32 + rl;
  const int dW = (w * 32) * 64;  // wave-uniform LDS u16 offset

  const int wm = (w >> 1) * 64;
  const int wn = (w & 1) * 64;
  const int fr = lane & 15;
  const int q = lane >> 4;

  f32x4 acc[4][4];
#pragma unroll
  for (int i = 0; i < 4; i++)
#pragma unroll
    for (int j = 0; j < 4; j++) acc[i][j] = f32x4{0.f, 0.f, 0.f, 0.f};

  auto stage = [&](int buf, int k0) {
    u16* a = &As[buf][0] + dW;
    u16* b = &Bs[buf][0] + dW;
#pragma unroll
    for (int g = 0; g < 4; g++) {
      gload16(A + (size_t)(rA + g * 8) * NN + k0 + swz, a + g * 8 * 64);
      gload16(Xi + (size_t)(rB + g * 8) * NN + k0 + swz, b + g * 8 * 64);
    }
  };
  auto compute = [&](int buf) {
    const u16* a = &As[buf][0];
    const u16* b = &Bs[buf][0];
#pragma unroll
    for (int kk = 0; kk < 2; kk++) {
      const int fo = ((kk * 4 + q) ^ (fr & 7)) * 8;  // phys chunk un-swizzle
      s16x8 af[4], bfr[4];
#pragma unroll
      for (int i = 0; i < 4; i++)
        af[i] = *(const s16x8*)&a[(wm + i * 16 + fr) * 64 + fo];
#pragma unroll
      for (int j = 0; j < 4; j++)
        bfr[j] = *(const s16x8*)&b[(wn + j * 16 + fr) * 64 + fo];
#pragma unroll
      for (int i = 0; i < 4; i++)
#pragma unroll
        for (int j = 0; j < 4; j++)
          acc[i][j] = __builtin_amdgcn_mfma_f32_16x16x32_bf16(af[i], bfr[j], acc[i][j], 0, 0, 0);
    }
  };

  stage(0, 0);
  stage(1, 64);
#pragma unroll 1
  for (int tI = 0; tI < 14; tI++) {
    CHEB_WAIT(8);                       // tile tI landed (tI+1 in flight)
    compute(tI & 1);
    __builtin_amdgcn_s_barrier();       // readers done before overwrite
    stage(tI & 1, (tI + 2) * 64);
  }
  CHEB_WAIT(8); compute(0);             // tI=14
  CHEB_WAIT(0); compute(1);             // tI=15

  const int nr0 = (lane >> 4) << 2;
#pragma unroll
  for (int i = 0; i < 4; i++) {
    const int node = m0 + wm + i * 16 + nr0;
#pragma unroll
    for (int j = 0; j < 4; j++) {
      const int colg = n0 + wn + j * 16 + fr;
      f32x4 c = acc[i][j];
      u16x4 o;
      o.x = f2bf(c.x); o.y = f2bf(c.y); o.z = f2bf(c.z); o.w = f2bf(c.w);
      *(u16x4*)&Xo[(size_t)colg * NN + node] = o;
    }
  }
}

// ---------------- 128x128xK=1024 GEMM core (verified R2 pipeline) ----------------
// C[m][col] = A[m][:] . Xi[col][:],  write Xo[col][m] (bf16).
// LDS buffer: [128 rows][4 chunks of 16B]; logical chunk c of row r at
// physical chunk c^((r>>1)&3) (staged via pre-swizzled global source addr).

__device__ __forceinline__ void gemm128_core(
    const u16* __restrict__ A, const u16* __restrict__ Xi, u16* __restrict__ Xo,
    int m0, int n0, int t, u16* AsB, u16* BsB) {
  const int lane = t & 63;
  const int w = t >> 6;

  // staging: wave w covers rows [w*32, w*32+32), 2 gloads x 16 rows per matrix.
  const int swz = ((lane & 3) ^ ((lane >> 3) & 3)) * 8;  // u16 offset in row
  const int rl = lane >> 2;
  const u16* pA0 = A + (size_t)(m0 + w * 32 + rl) * NN + swz;
  const u16* pA1 = pA0 + (size_t)16 * NN;
  const u16* pB0 = Xi + (size_t)(n0 + w * 32 + rl) * NN + swz;
  const u16* pB1 = pB0 + (size_t)16 * NN;
  const int db0 = (w * 32) * 32;        // LDS u16 offset, wave-uniform
  const int db1 = (w * 32 + 16) * 32;

  const int wm = (w >> 1) * 64;
  const int wn = (w & 1) * 64;
  const int fr = lane & 15;
  const int q = lane >> 4;
  // frag read: row = base+fr, logical chunk q -> physical q^((fr>>1)&3)
  const int fo = (q ^ ((fr >> 1) & 3)) * 8;

  f32x4 acc[4][4];
#pragma unroll
  for (int i = 0; i < 4; i++)
#pragma unroll
    for (int j = 0; j < 4; j++) acc[i][j] = f32x4{0.f, 0.f, 0.f, 0.f};

  auto stage = [&](u16* dA, u16* dB) {
    gload16(pA0, dA + db0);
    gload16(pA1, dA + db1);
    gload16(pB0, dB + db0);
    gload16(pB1, dB + db1);
    pA0 += 32; pA1 += 32; pB0 += 32; pB1 += 32;
  };
  auto compute = [&](const u16* cA, const u16* cB) {
    s16x8 af[4], bfr[4];
#pragma unroll
    for (int i = 0; i < 4; i++)
      af[i] = *(const s16x8*)&cA[(wm + i * 16 + fr) * 32 + fo];
#pragma unroll
    for (int j = 0; j < 4; j++)
      bfr[j] = *(const s16x8*)&cB[(wn + j * 16 + fr) * 32 + fo];
#pragma unroll
    for (int i = 0; i < 4; i++)
#pragma unroll
      for (int j = 0; j < 4; j++)
        acc[i][j] = __builtin_amdgcn_mfma_f32_16x16x32_bf16(af[i], bfr[j], acc[i][j], 0, 0, 0);
  };

  u16* a0 = AsB;  u16* a1 = AsB + 128 * 32;  u16* a2 = AsB + 2 * 128 * 32;
  u16* b0 = BsB;  u16* b1 = BsB + 128 * 32;  u16* b2 = BsB + 2 * 128 * 32;

  // pipeline: stage t=0,1; steady state keeps 8 loads in flight, waits only
  // for the 2-iteration-old tile (vmcnt(4)); vmcnt(0) only at the last step.
  stage(a0, b0);
  stage(a1, b1);
#pragma unroll 1
  for (int it = 0; it < 10; it++) {  // t = 3*it + {0,1,2}, t in [0,30)
    CHEB_WAIT(4); stage(a2, b2); compute(a0, b0);
    CHEB_WAIT(4); stage(a0, b0); compute(a1, b1);
    CHEB_WAIT(4); stage(a1, b1); compute(a2, b2);
  }
  CHEB_WAIT(4); compute(a0, b0);  // t=30
  CHEB_WAIT(0); compute(a1, b1);  // t=31

  // C/D layout: col = lane&15, row = (lane>>4)*4 + reg
  const int nr0 = (lane >> 4) << 2;
#pragma unroll
  for (int i = 0; i < 4; i++) {
    const int node = m0 + wm + i * 16 + nr0;
#pragma unroll
    for (int j = 0; j < 4; j++) {
      const int colg = n0 + wn + j * 16 + fr;
      f32x4 c = acc[i][j];
      u16x4 o;
      o.x = f2bf(c.x); o.y = f2bf(c.y); o.z = f2bf(c.z); o.w = f2bf(c.w);
      *(u16x4*)&Xo[(size_t)colg * NN + node] = o;
    }
  }
}

// gconv: 1056 blocks = two 528-halves of the XCD-bijective decode.
//   half 0 (lid<528):  z? X3=S1 Xi : X1=S0 Xi
//   half 1 (lid>=528): z? Y4=SS1 Xi : Y2=SS0 Xi
__global__ __launch_bounds__(256, 3) void gconv_gemm(
    const u16* __restrict__ S0, const u16* __restrict__ S1,
    const u16* __restrict__ SS0, const u16* __restrict__ SS1,
    const u16* __restrict__ Xi,
    u16* __restrict__ X1, u16* __restrict__ X2,
    u16* __restrict__ X3, u16* __restrict__ X4) {
  __shared__ u16 As[3][128 * 32];
  __shared__ u16 Bs[3][128 * 32];
  const int lid = blockIdx.x;
  const int h = lid >= 528;
  const int l2 = h ? lid - 528 : lid;
  const int work = (l2 & 7) * 66 + (l2 >> 3);
  const int y = work & 7;     // node tile
  const int tt = work >> 3;   // 0..65
  const int x = tt % 33;      // col tile
  const int z = tt / 33;      // support
  const u16* A = h ? (z ? SS1 : SS0) : (z ? S1 : S0);
  u16* Xo = h ? (z ? X4 : X2) : (z ? X3 : X1);
  gemm128_core(A, Xi, Xo, y * 128, x * 128, threadIdx.x, &As[0][0], &Bs[0][0]);
}

// ---------------- projections (MFMA) ----------------
// A-LDS [64 n][PSTRIDE kp-local]: TWO K-phases (kp 0..191 = 6 chunks, then
// 192..351 = 5 chunks), burst-staged (all loads before writes).

__device__ __forceinline__ void proj_stage_ph(
    u16* A, const u16* __restrict__ X0, const u16* __restrict__ X1,
    const u16* __restrict__ X2, const u16* __restrict__ X3,
    const u16* __restrict__ X4, int b, int n0, int t, int kb, int nids) {
  u16x4 v[3][4];
#pragma unroll
  for (int i = 0; i < 3; i++) {  // ids: kpg = idx>>4 (4-kp group), n4 = (idx&15)*4
    const int idx = t + i * 256;
    if (idx < nids) {
      const int kp0 = kb + (idx >> 4) * 4;
      const int n4 = (idx & 15) * 4;
#pragma unroll
      for (int r = 0; r < 4; r++) {
        const int kp = kp0 + r;
        if (kp < 330) {
          const int m = kp / 66;
          const int f = kp - m * 66;
          const u16* Xm = m == 0 ? X0 : m == 1 ? X1 : m == 2 ? X2 : m == 3 ? X3 : X4;
          v[i][r] = *(const u16x4*)(Xm + (size_t)(f * 64 + b) * NN + n0 + n4);
        } else {
          v[i][r] = u16x4{0, 0, 0, 0};
        }
      }
    }
  }
#pragma unroll
  for (int i = 0; i < 3; i++) {
    const int idx = t + i * 256;
    if (idx < nids) {
      const int kpl = (idx >> 4) * 4;  // local kp offset within phase buffer
      const int n4 = (idx & 15) * 4;
#pragma unroll
      for (int c = 0; c < 4; c++) {
        u16x4 o;
        o.x = v[i][0][c]; o.y = v[i][1][c]; o.z = v[i][2][c]; o.w = v[i][3][c];
        *(u16x4*)&A[(n4 + c) * PSTRIDE + kpl] = o;
      }
    }
  }
}

// gconv1 projection: [64n x 330] @ W1 -> 128 outs; sigmoid; r*hx -> X0'^T; u -> uout.
// Wave split: wave w covers rows (w>>1)*32..+32, outputs half jh=w&1.
__global__ __launch_bounds__(256, 6) void proj1(
    const u16* __restrict__ X0, const u16* __restrict__ X1, const u16* __restrict__ X2,
    const u16* __restrict__ X3, const u16* __restrict__ X4,
    const u16* __restrict__ WF, const float* __restrict__ bias,
    const float* __restrict__ hx, u16* __restrict__ X0p, float* __restrict__ uout) {
  __shared__ u16 A[64 * PSTRIDE];
  const int t = threadIdx.x;
  const int n0 = blockIdx.x * 64;
  const int b = blockIdx.y;

  const int lane = t & 63;
  const int w = t >> 6;
  const int fr = lane & 15;
  const int q8 = (lane >> 4) * 8;
  const int nb = (w >> 1) * 32;
  const int jh = w & 1;
  const u16* arow = &A[(nb + fr) * PSTRIDE + q8];
  const u16* wfl = WF + (size_t)lane * 8;  // + (c*8 + jh*4 + j)*512

  f32x4 acc[2][4];
#pragma unroll
  for (int ii = 0; ii < 2; ii++)
#pragma unroll
    for (int j = 0; j < 4; j++) acc[ii][j] = f32x4{0.f, 0.f, 0.f, 0.f};

  // phase 0: kp 0..191 (6 chunks, 768 ids = exactly 3 iters)
  proj_stage_ph(A, X0, X1, X2, X3, X4, b, n0, t, 0, 768);
  __syncthreads();
  for (int c = 0; c < 6; c++) {
    s16x8 af[2];
#pragma unroll
    for (int ii = 0; ii < 2; ii++)
      af[ii] = *(const s16x8*)(arow + ii * 16 * PSTRIDE + c * 32);
#pragma unroll
    for (int j = 0; j < 4; j++) {
      const s16x8 bf = *(const s16x8*)(wfl + ((c * 8 + jh * 4 + j) << 9));
#pragma unroll
      for (int ii = 0; ii < 2; ii++)
        acc[ii][j] = __builtin_amdgcn_mfma_f32_16x16x32_bf16(af[ii], bf, acc[ii][j], 0, 0, 0);
    }
  }
  __syncthreads();  // phase-0 readers done before overwrite
  // phase 1: kp 192..351 (5 chunks, 640 ids)
  proj_stage_ph(A, X0, X1, X2, X3, X4, b, n0, t, 192, 640);
  __syncthreads();
  for (int c = 6; c < 11; c++) {
    s16x8 af[2];
#pragma unroll
    for (int ii = 0; ii < 2; ii++)
      af[ii] = *(const s16x8*)(arow + ii * 16 * PSTRIDE + (c - 6) * 32);
#pragma unroll
    for (int j = 0; j < 4; j++) {
      const s16x8 bf = *(const s16x8*)(wfl + ((c * 8 + jh * 4 + j) << 9));
#pragma unroll
      for (int ii = 0; ii < 2; ii++)
        acc[ii][j] = __builtin_amdgcn_mfma_f32_16x16x32_bf16(af[ii], bf, acc[ii][j], 0, 0, 0);
    }
  }

  // D layout: col(o within sub) = lane&15, row(n within sub) = (lane>>4)*4 + reg
  const int nl0 = (lane >> 4) * 4;
#pragma unroll
  for (int ii = 0; ii < 2; ii++) {
    const int n = n0 + nb + ii * 16 + nl0;  // + reg
#pragma unroll
    for (int j = 0; j < 4; j++) {
      const int ol = j * 16 + fr;           // o within half
      const float bs = bias[jh * 64 + ol];
      f32x4 v;
      v.x = 1.f / (1.f + __expf(-(acc[ii][j].x + bs)));
      v.y = 1.f / (1.f + __expf(-(acc[ii][j].y + bs)));
      v.z = 1.f / (1.f + __expf(-(acc[ii][j].z + bs)));
      v.w = 1.f / (1.f + __expf(-(acc[ii][j].w + bs)));
      if (jh == 0) {  // r-part -> X0'^T row (2+ol)*64+b, times hx
        const float* hxp = hx + ((size_t)b << 16) + (size_t)n * 64 + ol;
        u16x4 s;
        s.x = f2bf(v.x * hxp[0 * 64]);
        s.y = f2bf(v.y * hxp[1 * 64]);
        s.z = f2bf(v.z * hxp[2 * 64]);
        s.w = f2bf(v.w * hxp[3 * 64]);
        *(u16x4*)&X0p[(size_t)((2 + ol) * 64 + b) * NN + n] = s;
      } else {  // u-part -> uout (d_out scratch)
        float* up = uout + (((size_t)b << 10) + n) * 64 + ol;
        up[0 * 64] = v.x; up[1 * 64] = v.y; up[2 * 64] = v.z; up[3 * 64] = v.w;
      }
    }
  }
}

// gconv2 projection: tanh + GRU blend. uin aliases out (same layout) - no restrict.
__global__ __launch_bounds__(256, 6) void proj2(
    const u16* __restrict__ X0, const u16* __restrict__ X1, const u16* __restrict__ X2,
    const u16* __restrict__ X3, const u16* __restrict__ X4,
    const u16* __restrict__ WF, const float* __restrict__ bias,
    const float* __restrict__ hx, const float* uin, float* out) {
  __shared__ u16 A[64 * PSTRIDE];
  const int t = threadIdx.x;
  const int n0 = blockIdx.x * 64;
  const int b = blockIdx.y;

  const int lane = t & 63;
  const int w = t >> 6;
  const int fr = lane & 15;
  const int q8 = (lane >> 4) * 8;
  const int nb = (w >> 1) * 32;
  const int jh = w & 1;
  const u16* arow = &A[(nb + fr) * PSTRIDE + q8];
  const u16* wfl = WF + (size_t)lane * 8;  // + (c*4 + jh*2 + j)*512

  f32x4 acc[2][2];
#pragma unroll
  for (int ii = 0; ii < 2; ii++)
#pragma unroll
    for (int j = 0; j < 2; j++) acc[ii][j] = f32x4{0.f, 0.f, 0.f, 0.f};

  proj_stage_ph(A, X0, X1, X2, X3, X4, b, n0, t, 0, 768);
  __syncthreads();
  for (int c = 0; c < 6; c++) {
    s16x8 af[2];
#pragma unroll
    for (int ii = 0; ii < 2; ii++)
      af[ii] = *(const s16x8*)(arow + ii * 16 * PSTRIDE + c * 32);
#pragma unroll
    for (int j = 0; j < 2; j++) {
      const s16x8 bf = *(const s16x8*)(wfl + ((c * 4 + jh * 2 + j) << 9));
#pragma unroll
      for (int ii = 0; ii < 2; ii++)
        acc[ii][j] = __builtin_amdgcn_mfma_f32_16x16x32_bf16(af[ii], bf, acc[ii][j], 0, 0, 0);
    }
  }
  __syncthreads();
  proj_stage_ph(A, X0, X1, X2, X3, X4, b, n0, t, 192, 640);
  __syncthreads();
  for (int c = 6; c < 11; c++) {
    s16x8 af[2];
#pragma unroll
    for (int ii = 0; ii < 2; ii++)
      af[ii] = *(const s16x8*)(arow + ii * 16 * PSTRIDE + (c - 6) * 32);
#pragma unroll
    for (int j = 0; j < 2; j++) {
      const s16x8 bf = *(const s16x8*)(wfl + ((c * 4 + jh * 2 + j) << 9));
#pragma unroll
      for (int ii = 0; ii < 2; ii++)
        acc[ii][j] = __builtin_amdgcn_mfma_f32_16x16x32_bf16(af[ii], bf, acc[ii][j], 0, 0, 0);
    }
  }

  const int nl0 = (lane >> 4) * 4;
#pragma unroll
  for (int ii = 0; ii < 2; ii++) {
    const int n = n0 + nb + ii * 16 + nl0;  // + reg
#pragma unroll
    for (int j = 0; j < 2; j++) {
      const int o = jh * 32 + j * 16 + fr;
      const float bs = bias[o];
      const size_t base = (((size_t)b << 10) + n) * 64 + o;  // + reg*64
      float c0 = tanhf(acc[ii][j].x + bs);
      float c1 = tanhf(acc[ii][j].y + bs);
      float c2 = tanhf(acc[ii][j].z + bs);
      float c3 = tanhf(acc[ii][j].w + bs);
      float u0 = uin[base + 0 * 64], u1 = uin[base + 1 * 64];
      float u2 = uin[base + 2 * 64], u3 = uin[base + 3 * 64];
      float h0 = hx[base + 0 * 64], h1 = hx[base + 1 * 64];
      float h2 = hx[base + 2 * 64], h3 = hx[base + 3 * 64];
      out[base + 0 * 64] = u0 * h0 + (1.f - u0) * c0;
      out[base + 1 * 64] = u1 * h1 + (1.f - u1) * c1;
      out[base + 2 * 64] = u2 * h2 + (1.f - u2) * c2;
      out[base + 3 * 64] = u3 * h3 + (1.f - u3) * c3;
    }
  }
}

// ---------------- launch ----------------

extern "C" void kernel_launch(void* const* d_in, const int* in_sizes, int n_in,
                              void* d_out, int out_size, void* d_ws, size_t ws_size,
                              hipStream_t stream) {
  (void)in_sizes; (void)n_in; (void)out_size; (void)ws_size;
  const float* inp = (const float*)d_in[0];
  const float* hx  = (const float*)d_in[1];
  const float* s0  = (const float*)d_in[2];
  const float* s1  = (const float*)d_in[3];
  const float* Wo  = (const float*)d_in[4];
  const float* bo  = (const float*)d_in[5];
  const float* Wu  = (const float*)d_in[6];
  const float* bu  = (const float*)d_in[7];
  float* out = (float*)d_out;

  char* p = (char*)d_ws;
  u16* Sb0 = (u16*)p; p += (size_t)NN * NN * 2;
  u16* Sb1 = (u16*)p; p += (size_t)NN * NN * 2;
  u16* SSb0 = (u16*)p; p += (size_t)NN * NN * 2;
  u16* SSb1 = (u16*)p; p += (size_t)NN * NN * 2;
  const size_t xbytes = (size_t)NCOLS * NN * 2;
  u16* X0T = (u16*)p; p += xbytes;
  u16* X1T = (u16*)p; p += xbytes;
  u16* X2T = (u16*)p; p += xbytes;
  u16* X3T = (u16*)p; p += xbytes;
  u16* X4T = (u16*)p; p += xbytes;
  u16* X0P = (u16*)p; p += xbytes;
  u16* WF1 = (u16*)p; p += (size_t)11 * 8 * 512 * 2;  // 90112 B
  u16* WF2 = (u16*)p; p += (size_t)11 * 4 * 512 * 2;  // 45056 B
  // ST scratch: X1T/X3T are not written until gconv1, free for sq_gemm input.
  u16* ST0 = X1T;
  u16* ST1 = X3T;
  // total ws use: 8 MB + 6*8.25 MB + ~132 KB

  // one pack launch: supports (512 blocks) + X0^T (1024) + WF (33)
  pack_all<<<dim3(1569), dim3(256), 0, stream>>>(
      s0, s1, inp, hx, Wo, Wu, Sb0, Sb1, ST0, ST1, X0T, X0P, WF1, WF2);
  sq_gemm<<<dim3(128), dim3(256), 0, stream>>>(Sb0, Sb1, ST0, ST1, SSb0, SSb1);
  // gconv1: X1=S0 X0, X3=S1 X0, Y2=SS0 X0, Y4=SS1 X0 (one launch; fold in WF)
  gconv_gemm<<<dim3(1056), dim3(256), 0, stream>>>(Sb0, Sb1, SSb0, SSb1, X0T,
                                                   X1T, X2T, X3T, X4T);
  proj1<<<dim3(16, 64), dim3(256), 0, stream>>>(X0T, X1T, X2T, X3T, X4T, WF1, bo, hx, X0P, out);
  // gconv2 on X0'
  gconv_gemm<<<dim3(1056), dim3(256), 0, stream>>>(Sb0, Sb1, SSb0, SSb1, X0P,
                                                   X1T, X2T, X3T, X4T);
  proj2<<<dim3(16, 64), dim3(256), 0, stream>>>(X0P, X1T, X2T, X3T, X4T, WF2, bu, hx, out, out);
}

// Round 13
// 258.943 us; speedup vs baseline: 1.0486x; 1.0097x over previous
//
#include <hip/hip_runtime.h>

// DCGRU cell, MI355X.  (R12 base + T14 async-STAGE split in proj1/proj2.)
//   Diffusion intermediates TRANSPOSED: XT[col = f*64+b][node n] in bf16.
//   pack_all (one launch): supports->bf16+transpose | X0^T build | WF fold.
//   sq_gemm (once): SS_z = S_z @ S_z, BK=64 double-buffered deep pipe.
//   gconv_gemm: 1056 blocks = two 528-halves of verified 128x128 decode;
//     BK=32, TRIPLE-buffered LDS, counted vmcnt(4). XOR swizzle via
//     pre-swizzled GLOBAL source. Chebyshev "2Y-X0" folded into W.
//   proj1/proj2: TWO-PHASE K staging into A[64][200] (25.6KB; 200 u16 =
//     25x16B units, 25=1 mod 8 -> conflict-free ds_read_b128 A-frags).
//     T14 async split: phase-1 global loads ISSUED BEFORE phase-0 MFMAs
//     (held in regs), LDS write after the post-compute barrier -> staging
//     latency hides under the 6-chunk MFMA block. Wave split: 32 n-rows x
//     half the o-outputs. WF in fragment order (coalesced 1KB/wave).
//   d_out doubles as u-buffer.

typedef unsigned short u16;
typedef unsigned int u32;
typedef short s16x8 __attribute__((ext_vector_type(8)));
typedef float f32x4 __attribute__((ext_vector_type(4)));
typedef u16 u16x4 __attribute__((ext_vector_type(4)));

#define NN 1024
#define NB 64
#define NF 66
#define NCOLS 4224  // NF*NB
#define KPAD 352    // 330 padded to 11*32
#define PSTRIDE 200 // proj A-LDS row stride in u16 (400B = 25x16B, odd units)

__device__ __forceinline__ u16 f2bf(float f) {
  u32 u = __builtin_bit_cast(u32, f);
  u = (u + 0x7fffu + ((u >> 16) & 1u)) >> 16;  // RNE
  return (u16)u;
}
__device__ __forceinline__ float bf2f(u16 h) {
  u32 u = ((u32)h) << 16;
  return __builtin_bit_cast(float, u);
}

__device__ __forceinline__ void gload16(const void* g, void* l) {
  __builtin_amdgcn_global_load_lds(
      (const __attribute__((address_space(1))) u32*)g,
      (__attribute__((address_space(3))) u32*)l, 16, 0, 0);
}

// counted-vmcnt barrier: own oldest loads landed -> barrier -> fence reads
#define CHEB_WAIT(N)                                      \
  do {                                                    \
    asm volatile("s_waitcnt vmcnt(" #N ")" ::: "memory"); \
    __builtin_amdgcn_s_barrier();                         \
    asm volatile("" ::: "memory");                        \
  } while (0)

// ---------------- merged pack kernel ----------------
// blocks [0,512): supports; [512,1536): X0^T; [1536,1569): WF fold.
__global__ __launch_bounds__(256) void pack_all(
    const float* __restrict__ s0, const float* __restrict__ s1,
    const float* __restrict__ inp, const float* __restrict__ hx,
    const float* __restrict__ Wo, const float* __restrict__ Wu,
    u16* __restrict__ Sb0, u16* __restrict__ Sb1,
    u16* __restrict__ ST0, u16* __restrict__ ST1,
    u16* __restrict__ x0t, u16* __restrict__ x0pt,
    u16* __restrict__ WF1, u16* __restrict__ WF2) {
  __shared__ float tile[64][65];
  const int bid = blockIdx.x;
  const int t = threadIdx.x;

  if (bid < 512) {  // ---- supports ----
    const int z = bid >> 8;
    const int bx = bid & 255;
    const float* S = z ? s1 : s0;
    u16* D = z ? Sb1 : Sb0;
    u16* T = z ? ST1 : ST0;
    const int r0 = (bx >> 4) * 64, c0 = (bx & 15) * 64;
    int cc4 = (t & 15) * 4, rr = t >> 4;
#pragma unroll
    for (int p = 0; p < 4; p++) {
      int r = p * 16 + rr;
      f32x4 v = *(const f32x4*)(S + (size_t)(r0 + r) * NN + c0 + cc4);
      tile[r][cc4] = v.x; tile[r][cc4 + 1] = v.y;
      tile[r][cc4 + 2] = v.z; tile[r][cc4 + 3] = v.w;
      u16x4 o;
      o.x = f2bf(v.x); o.y = f2bf(v.y); o.z = f2bf(v.z); o.w = f2bf(v.w);
      *(u16x4*)&D[(size_t)(r0 + r) * NN + c0 + cc4] = o;
    }
    __syncthreads();
    int rr4 = (t & 15) * 4, cc = t >> 4;
#pragma unroll
    for (int p = 0; p < 4; p++) {
      int c = p * 16 + cc;
      u16x4 o;
      o.x = f2bf(tile[rr4][c]);     o.y = f2bf(tile[rr4 + 1][c]);
      o.z = f2bf(tile[rr4 + 2][c]); o.w = f2bf(tile[rr4 + 3][c]);
      *(u16x4*)&T[(size_t)(c0 + c) * NN + r0 + rr4] = o;
    }
  } else if (bid < 1536) {  // ---- X0^T ----
    const int idx = bid - 512;
    const int n0 = (idx & 15) * 64, b = idx >> 4;
    if (t < 32) {  // f=0,1: x0t[f*64+b][n] = inputs[b][2n+f]
      const int f = t >> 4;
      const int n4 = (t & 15) * 4;
      const float* src = inp + b * 2048 + (n0 + n4) * 2 + f;
      u16x4 o;
      o.x = f2bf(src[0]); o.y = f2bf(src[2]); o.z = f2bf(src[4]); o.w = f2bf(src[6]);
      size_t off = (size_t)(f * 64 + b) * NN + n0 + n4;
      *(u16x4*)(x0t + off) = o;
      *(u16x4*)(x0pt + off) = o;
    }
    int u4 = (t & 15) * 4, r0 = t >> 4;
#pragma unroll
    for (int p = 0; p < 4; p++) {
      int row = p * 16 + r0;
      f32x4 v = *(const f32x4*)(hx + ((size_t)b << 16) + (size_t)(n0 + row) * 64 + u4);
      tile[row][u4] = v.x; tile[row][u4 + 1] = v.y;
      tile[row][u4 + 2] = v.z; tile[row][u4 + 3] = v.w;
    }
    __syncthreads();
    int n4 = (t & 15) * 4, uu0 = t >> 4;
#pragma unroll
    for (int p = 0; p < 4; p++) {
      int u = p * 16 + uu0;
      u16x4 o;
      o.x = f2bf(tile[n4][u]);     o.y = f2bf(tile[n4 + 1][u]);
      o.z = f2bf(tile[n4 + 2][u]); o.w = f2bf(tile[n4 + 3][u]);
      *(u16x4*)&x0t[(size_t)((2 + u) * 64 + b) * NN + n0 + n4] = o;
    }
  } else {  // ---- WF fold ----
    const int gid = (bid - 1536) * 256 + t;
    const int pair = gid >> 6;   // 0..131
    const int lane = gid & 63;
    const int c = pair % 11;
    int jj = pair / 11;          // 0..11
    const float* W; u16* WF; int ldo, nj;
    if (jj < 8) { W = Wo; WF = WF1; ldo = 128; nj = 8; }
    else        { jj -= 8; W = Wu; WF = WF2; ldo = 64; nj = 4; }
    const int o = jj * 16 + (lane & 15);
    const int kpb = c * 32 + (lane >> 4) * 8;
    u16 vals[8];
#pragma unroll
    for (int e = 0; e < 8; e++) {
      const int kp = kpb + e;
      float v = 0.f;
      if (kp < 330) {
        const int m = kp / 66;
        const int f = kp - m * 66;
        const float* Wrow = W + (size_t)(f * 5) * ldo + o;
        if (m == 0)      v = Wrow[0] - Wrow[2 * ldo] - Wrow[4 * ldo];
        else if (m == 2) v = 2.f * Wrow[2 * ldo];
        else if (m == 4) v = 2.f * Wrow[4 * ldo];
        else             v = Wrow[(size_t)m * ldo];
      }
      vals[e] = f2bf(v);
    }
    u16* dst = WF + (((size_t)(c * nj + jj) << 6) + lane) * 8;
#pragma unroll
    for (int e = 0; e < 8; e++) dst[e] = vals[e];
  }
}

// SS_z = S_z @ S_z via A = ST_z, Xi = S_z. BK=64 double-buffered deep pipe.
__global__ __launch_bounds__(256) void sq_gemm(
    const u16* __restrict__ S0, const u16* __restrict__ S1,
    const u16* __restrict__ ST0, const u16* __restrict__ ST1,
    u16* __restrict__ SS0, u16* __restrict__ SS1) {
  __shared__ u16 As[2][128 * 64];
  __shared__ u16 Bs[2][128 * 64];
  const int t = threadIdx.x;
  const int lane = t & 63;
  const int w = t >> 6;
  const int lid = blockIdx.x;                  // 128 blocks
  const int work = (lid & 7) * 16 + (lid >> 3);
  const int z = work >> 6;
  const int rr = work & 63;
  const int y = rr >> 3, x = rr & 7;
  const u16* A = z ? ST1 : ST0;
  const u16* Xi = z ? S1 : S0;
  u16* Xo = z ? SS1 : SS0;
  const int m0 = y * 128, n0 = x * 128;

  const int swz = ((lane & 7) ^ (lane >> 3)) * 8;  // u16 offset in 64-elem row
  const int rl = lane >> 3;
  const int rA = m0 + w * 32 + rl;
  const int rB = n0 + w * 32 + rl;
  const int dW = (w * 32) * 64;  // wave-uniform LDS u16 offset

  const int wm = (w >> 1) * 64;
  const int wn = (w & 1) * 64;
  const int fr = lane & 15;
  const int q = lane >> 4;

  f32x4 acc[4][4];
#pragma unroll
  for (int i = 0; i < 4; i++)
#pragma unroll
    for (int j = 0; j < 4; j++) acc[i][j] = f32x4{0.f, 0.f, 0.f, 0.f};

  auto stage = [&](int buf, int k0) {
    u16* a = &As[buf][0] + dW;
    u16* b = &Bs[buf][0] + dW;
#pragma unroll
    for (int g = 0; g < 4; g++) {
      gload16(A + (size_t)(rA + g * 8) * NN + k0 + swz, a + g * 8 * 64);
      gload16(Xi + (size_t)(rB + g * 8) * NN + k0 + swz, b + g * 8 * 64);
    }
  };
  auto compute = [&](int buf) {
    const u16* a = &As[buf][0];
    const u16* b = &Bs[buf][0];
#pragma unroll
    for (int kk = 0; kk < 2; kk++) {
      const int fo = ((kk * 4 + q) ^ (fr & 7)) * 8;  // phys chunk un-swizzle
      s16x8 af[4], bfr[4];
#pragma unroll
      for (int i = 0; i < 4; i++)
        af[i] = *(const s16x8*)&a[(wm + i * 16 + fr) * 64 + fo];
#pragma unroll
      for (int j = 0; j < 4; j++)
        bfr[j] = *(const s16x8*)&b[(wn + j * 16 + fr) * 64 + fo];
#pragma unroll
      for (int i = 0; i < 4; i++)
#pragma unroll
        for (int j = 0; j < 4; j++)
          acc[i][j] = __builtin_amdgcn_mfma_f32_16x16x32_bf16(af[i], bfr[j], acc[i][j], 0, 0, 0);
    }
  };

  stage(0, 0);
  stage(1, 64);
#pragma unroll 1
  for (int tI = 0; tI < 14; tI++) {
    CHEB_WAIT(8);                       // tile tI landed (tI+1 in flight)
    compute(tI & 1);
    __builtin_amdgcn_s_barrier();       // readers done before overwrite
    stage(tI & 1, (tI + 2) * 64);
  }
  CHEB_WAIT(8); compute(0);             // tI=14
  CHEB_WAIT(0); compute(1);             // tI=15

  const int nr0 = (lane >> 4) << 2;
#pragma unroll
  for (int i = 0; i < 4; i++) {
    const int node = m0 + wm + i * 16 + nr0;
#pragma unroll
    for (int j = 0; j < 4; j++) {
      const int colg = n0 + wn + j * 16 + fr;
      f32x4 c = acc[i][j];
      u16x4 o;
      o.x = f2bf(c.x); o.y = f2bf(c.y); o.z = f2bf(c.z); o.w = f2bf(c.w);
      *(u16x4*)&Xo[(size_t)colg * NN + node] = o;
    }
  }
}

// ---------------- 128x128xK=1024 GEMM core (verified R2 pipeline) ----------------
__device__ __forceinline__ void gemm128_core(
    const u16* __restrict__ A, const u16* __restrict__ Xi, u16* __restrict__ Xo,
    int m0, int n0, int t, u16* AsB, u16* BsB) {
  const int lane = t & 63;
  const int w = t >> 6;

  const int swz = ((lane & 3) ^ ((lane >> 3) & 3)) * 8;  // u16 offset in row
  const int rl = lane >> 2;
  const u16* pA0 = A + (size_t)(m0 + w * 32 + rl) * NN + swz;
  const u16* pA1 = pA0 + (size_t)16 * NN;
  const u16* pB0 = Xi + (size_t)(n0 + w * 32 + rl) * NN + swz;
  const u16* pB1 = pB0 + (size_t)16 * NN;
  const int db0 = (w * 32) * 32;        // LDS u16 offset, wave-uniform
  const int db1 = (w * 32 + 16) * 32;

  const int wm = (w >> 1) * 64;
  const int wn = (w & 1) * 64;
  const int fr = lane & 15;
  const int q = lane >> 4;
  const int fo = (q ^ ((fr >> 1) & 3)) * 8;

  f32x4 acc[4][4];
#pragma unroll
  for (int i = 0; i < 4; i++)
#pragma unroll
    for (int j = 0; j < 4; j++) acc[i][j] = f32x4{0.f, 0.f, 0.f, 0.f};

  auto stage = [&](u16* dA, u16* dB) {
    gload16(pA0, dA + db0);
    gload16(pA1, dA + db1);
    gload16(pB0, dB + db0);
    gload16(pB1, dB + db1);
    pA0 += 32; pA1 += 32; pB0 += 32; pB1 += 32;
  };
  auto compute = [&](const u16* cA, const u16* cB) {
    s16x8 af[4], bfr[4];
#pragma unroll
    for (int i = 0; i < 4; i++)
      af[i] = *(const s16x8*)&cA[(wm + i * 16 + fr) * 32 + fo];
#pragma unroll
    for (int j = 0; j < 4; j++)
      bfr[j] = *(const s16x8*)&cB[(wn + j * 16 + fr) * 32 + fo];
#pragma unroll
    for (int i = 0; i < 4; i++)
#pragma unroll
      for (int j = 0; j < 4; j++)
        acc[i][j] = __builtin_amdgcn_mfma_f32_16x16x32_bf16(af[i], bfr[j], acc[i][j], 0, 0, 0);
  };

  u16* a0 = AsB;  u16* a1 = AsB + 128 * 32;  u16* a2 = AsB + 2 * 128 * 32;
  u16* b0 = BsB;  u16* b1 = BsB + 128 * 32;  u16* b2 = BsB + 2 * 128 * 32;

  stage(a0, b0);
  stage(a1, b1);
#pragma unroll 1
  for (int it = 0; it < 10; it++) {  // t = 3*it + {0,1,2}, t in [0,30)
    CHEB_WAIT(4); stage(a2, b2); compute(a0, b0);
    CHEB_WAIT(4); stage(a0, b0); compute(a1, b1);
    CHEB_WAIT(4); stage(a1, b1); compute(a2, b2);
  }
  CHEB_WAIT(4); compute(a0, b0);  // t=30
  CHEB_WAIT(0); compute(a1, b1);  // t=31

  const int nr0 = (lane >> 4) << 2;
#pragma unroll
  for (int i = 0; i < 4; i++) {
    const int node = m0 + wm + i * 16 + nr0;
#pragma unroll
    for (int j = 0; j < 4; j++) {
      const int colg = n0 + wn + j * 16 + fr;
      f32x4 c = acc[i][j];
      u16x4 o;
      o.x = f2bf(c.x); o.y = f2bf(c.y); o.z = f2bf(c.z); o.w = f2bf(c.w);
      *(u16x4*)&Xo[(size_t)colg * NN + node] = o;
    }
  }
}

// gconv: 1056 blocks = two 528-halves of the XCD-bijective decode.
__global__ __launch_bounds__(256, 3) void gconv_gemm(
    const u16* __restrict__ S0, const u16* __restrict__ S1,
    const u16* __restrict__ SS0, const u16* __restrict__ SS1,
    const u16* __restrict__ Xi,
    u16* __restrict__ X1, u16* __restrict__ X2,
    u16* __restrict__ X3, u16* __restrict__ X4) {
  __shared__ u16 As[3][128 * 32];
  __shared__ u16 Bs[3][128 * 32];
  const int lid = blockIdx.x;
  const int h = lid >= 528;
  const int l2 = h ? lid - 528 : lid;
  const int work = (l2 & 7) * 66 + (l2 >> 3);
  const int y = work & 7;     // node tile
  const int tt = work >> 3;   // 0..65
  const int x = tt % 33;      // col tile
  const int z = tt / 33;      // support
  const u16* A = h ? (z ? SS1 : SS0) : (z ? S1 : S0);
  u16* Xo = h ? (z ? X4 : X2) : (z ? X3 : X1);
  gemm128_core(A, Xi, Xo, y * 128, x * 128, threadIdx.x, &As[0][0], &Bs[0][0]);
}

// ---------------- projections (MFMA) ----------------
// T14 async split: gather (global->regs) separated from write (regs->LDS).

struct PV { u16x4 v[3][4]; };

__device__ __forceinline__ void proj_gather(
    PV& P, const u16* __restrict__ X0, const u16* __restrict__ X1,
    const u16* __restrict__ X2, const u16* __restrict__ X3,
    const u16* __restrict__ X4, int b, int n0, int t, int kb, int nids) {
#pragma unroll
  for (int i = 0; i < 3; i++) {
    const int idx = t + i * 256;
    if (idx < nids) {
      const int kp0 = kb + (idx >> 4) * 4;
      const int n4 = (idx & 15) * 4;
#pragma unroll
      for (int r = 0; r < 4; r++) {
        const int kp = kp0 + r;
        if (kp < 330) {
          const int m = kp / 66;
          const int f = kp - m * 66;
          const u16* Xm = m == 0 ? X0 : m == 1 ? X1 : m == 2 ? X2 : m == 3 ? X3 : X4;
          P.v[i][r] = *(const u16x4*)(Xm + (size_t)(f * 64 + b) * NN + n0 + n4);
        } else {
          P.v[i][r] = u16x4{0, 0, 0, 0};
        }
      }
    }
  }
}

__device__ __forceinline__ void proj_write(
    const PV& P, u16* A, int t, int nids) {
#pragma unroll
  for (int i = 0; i < 3; i++) {
    const int idx = t + i * 256;
    if (idx < nids) {
      const int kpl = (idx >> 4) * 4;  // local kp offset within phase buffer
      const int n4 = (idx & 15) * 4;
#pragma unroll
      for (int c = 0; c < 4; c++) {
        u16x4 o;
        o.x = P.v[i][0][c]; o.y = P.v[i][1][c]; o.z = P.v[i][2][c]; o.w = P.v[i][3][c];
        *(u16x4*)&A[(n4 + c) * PSTRIDE + kpl] = o;
      }
    }
  }
}

// gconv1 projection: [64n x 330] @ W1 -> 128 outs; sigmoid; r*hx -> X0'^T; u -> uout.
__global__ __launch_bounds__(256, 5) void proj1(
    const u16* __restrict__ X0, const u16* __restrict__ X1, const u16* __restrict__ X2,
    const u16* __restrict__ X3, const u16* __restrict__ X4,
    const u16* __restrict__ WF, const float* __restrict__ bias,
    const float* __restrict__ hx, u16* __restrict__ X0p, float* __restrict__ uout) {
  __shared__ u16 A[64 * PSTRIDE];
  const int t = threadIdx.x;
  const int n0 = blockIdx.x * 64;
  const int b = blockIdx.y;

  const int lane = t & 63;
  const int w = t >> 6;
  const int fr = lane & 15;
  const int q8 = (lane >> 4) * 8;
  const int nb = (w >> 1) * 32;
  const int jh = w & 1;
  const u16* arow = &A[(nb + fr) * PSTRIDE + q8];
  const u16* wfl = WF + (size_t)lane * 8;  // + (c*8 + jh*4 + j)*512

  f32x4 acc[2][4];
#pragma unroll
  for (int ii = 0; ii < 2; ii++)
#pragma unroll
    for (int j = 0; j < 4; j++) acc[ii][j] = f32x4{0.f, 0.f, 0.f, 0.f};

  // phase 0: kp 0..191 (6 chunks, 768 ids)
  PV P0;
  proj_gather(P0, X0, X1, X2, X3, X4, b, n0, t, 0, 768);
  proj_write(P0, A, t, 768);
  __syncthreads();
  // T14: issue phase-1 loads EARLY -- they land while phase-0 MFMAs run
  PV P1;
  proj_gather(P1, X0, X1, X2, X3, X4, b, n0, t, 192, 640);
  for (int c = 0; c < 6; c++) {
    s16x8 af[2];
#pragma unroll
    for (int ii = 0; ii < 2; ii++)
      af[ii] = *(const s16x8*)(arow + ii * 16 * PSTRIDE + c * 32);
#pragma unroll
    for (int j = 0; j < 4; j++) {
      const s16x8 bf = *(const s16x8*)(wfl + ((c * 8 + jh * 4 + j) << 9));
#pragma unroll
      for (int ii = 0; ii < 2; ii++)
        acc[ii][j] = __builtin_amdgcn_mfma_f32_16x16x32_bf16(af[ii], bf, acc[ii][j], 0, 0, 0);
    }
  }
  __syncthreads();  // phase-0 readers done before overwrite
  proj_write(P1, A, t, 640);
  __syncthreads();
  for (int c = 6; c < 11; c++) {
    s16x8 af[2];
#pragma unroll
    for (int ii = 0; ii < 2; ii++)
      af[ii] = *(const s16x8*)(arow + ii * 16 * PSTRIDE + (c - 6) * 32);
#pragma unroll
    for (int j = 0; j < 4; j++) {
      const s16x8 bf = *(const s16x8*)(wfl + ((c * 8 + jh * 4 + j) << 9));
#pragma unroll
      for (int ii = 0; ii < 2; ii++)
        acc[ii][j] = __builtin_amdgcn_mfma_f32_16x16x32_bf16(af[ii], bf, acc[ii][j], 0, 0, 0);
    }
  }

  // D layout: col(o within sub) = lane&15, row(n within sub) = (lane>>4)*4 + reg
  const int nl0 = (lane >> 4) * 4;
#pragma unroll
  for (int ii = 0; ii < 2; ii++) {
    const int n = n0 + nb + ii * 16 + nl0;  // + reg
#pragma unroll
    for (int j = 0; j < 4; j++) {
      const int ol = j * 16 + fr;           // o within half
      const float bs = bias[jh * 64 + ol];
      f32x4 v;
      v.x = 1.f / (1.f + __expf(-(acc[ii][j].x + bs)));
      v.y = 1.f / (1.f + __expf(-(acc[ii][j].y + bs)));
      v.z = 1.f / (1.f + __expf(-(acc[ii][j].z + bs)));
      v.w = 1.f / (1.f + __expf(-(acc[ii][j].w + bs)));
      if (jh == 0) {  // r-part -> X0'^T row (2+ol)*64+b, times hx
        const float* hxp = hx + ((size_t)b << 16) + (size_t)n * 64 + ol;
        u16x4 s;
        s.x = f2bf(v.x * hxp[0 * 64]);
        s.y = f2bf(v.y * hxp[1 * 64]);
        s.z = f2bf(v.z * hxp[2 * 64]);
        s.w = f2bf(v.w * hxp[3 * 64]);
        *(u16x4*)&X0p[(size_t)((2 + ol) * 64 + b) * NN + n] = s;
      } else {  // u-part -> uout (d_out scratch)
        float* up = uout + (((size_t)b << 10) + n) * 64 + ol;
        up[0 * 64] = v.x; up[1 * 64] = v.y; up[2 * 64] = v.z; up[3 * 64] = v.w;
      }
    }
  }
}

// gconv2 projection: tanh + GRU blend. uin aliases out (same layout) - no restrict.
__global__ __launch_bounds__(256, 5) void proj2(
    const u16* __restrict__ X0, const u16* __restrict__ X1, const u16* __restrict__ X2,
    const u16* __restrict__ X3, const u16* __restrict__ X4,
    const u16* __restrict__ WF, const float* __restrict__ bias,
    const float* __restrict__ hx, const float* uin, float* out) {
  __shared__ u16 A[64 * PSTRIDE];
  const int t = threadIdx.x;
  const int n0 = blockIdx.x * 64;
  const int b = blockIdx.y;

  const int lane = t & 63;
  const int w = t >> 6;
  const int fr = lane & 15;
  const int q8 = (lane >> 4) * 8;
  const int nb = (w >> 1) * 32;
  const int jh = w & 1;
  const u16* arow = &A[(nb + fr) * PSTRIDE + q8];
  const u16* wfl = WF + (size_t)lane * 8;  // + (c*4 + jh*2 + j)*512

  f32x4 acc[2][2];
#pragma unroll
  for (int ii = 0; ii < 2; ii++)
#pragma unroll
    for (int j = 0; j < 2; j++) acc[ii][j] = f32x4{0.f, 0.f, 0.f, 0.f};

  PV P0;
  proj_gather(P0, X0, X1, X2, X3, X4, b, n0, t, 0, 768);
  proj_write(P0, A, t, 768);
  __syncthreads();
  PV P1;
  proj_gather(P1, X0, X1, X2, X3, X4, b, n0, t, 192, 640);
  for (int c = 0; c < 6; c++) {
    s16x8 af[2];
#pragma unroll
    for (int ii = 0; ii < 2; ii++)
      af[ii] = *(const s16x8*)(arow + ii * 16 * PSTRIDE + c * 32);
#pragma unroll
    for (int j = 0; j < 2; j++) {
      const s16x8 bf = *(const s16x8*)(wfl + ((c * 4 + jh * 2 + j) << 9));
#pragma unroll
      for (int ii = 0; ii < 2; ii++)
        acc[ii][j] = __builtin_amdgcn_mfma_f32_16x16x32_bf16(af[ii], bf, acc[ii][j], 0, 0, 0);
    }
  }
  __syncthreads();
  proj_write(P1, A, t, 640);
  __syncthreads();
  for (int c = 6; c < 11; c++) {
    s16x8 af[2];
#pragma unroll
    for (int ii = 0; ii < 2; ii++)
      af[ii] = *(const s16x8*)(arow + ii * 16 * PSTRIDE + (c - 6) * 32);
#pragma unroll
    for (int j = 0; j < 2; j++) {
      const s16x8 bf = *(const s16x8*)(wfl + ((c * 4 + jh * 2 + j) << 9));
#pragma unroll
      for (int ii = 0; ii < 2; ii++)
        acc[ii][j] = __builtin_amdgcn_mfma_f32_16x16x32_bf16(af[ii], bf, acc[ii][j], 0, 0, 0);
    }
  }

  const int nl0 = (lane >> 4) * 4;
#pragma unroll
  for (int ii = 0; ii < 2; ii++) {
    const int n = n0 + nb + ii * 16 + nl0;  // + reg
#pragma unroll
    for (int j = 0; j < 2; j++) {
      const int o = jh * 32 + j * 16 + fr;
      const float bs = bias[o];
      const size_t base = (((size_t)b << 10) + n) * 64 + o;  // + reg*64
      float c0 = tanhf(acc[ii][j].x + bs);
      float c1 = tanhf(acc[ii][j].y + bs);
      float c2 = tanhf(acc[ii][j].z + bs);
      float c3 = tanhf(acc[ii][j].w + bs);
      float u0 = uin[base + 0 * 64], u1 = uin[base + 1 * 64];
      float u2 = uin[base + 2 * 64], u3 = uin[base + 3 * 64];
      float h0 = hx[base + 0 * 64], h1 = hx[base + 1 * 64];
      float h2 = hx[base + 2 * 64], h3 = hx[base + 3 * 64];
      out[base + 0 * 64] = u0 * h0 + (1.f - u0) * c0;
      out[base + 1 * 64] = u1 * h1 + (1.f - u1) * c1;
      out[base + 2 * 64] = u2 * h2 + (1.f - u2) * c2;
      out[base + 3 * 64] = u3 * h3 + (1.f - u3) * c3;
    }
  }
}

// ---------------- launch ----------------

extern "C" void kernel_launch(void* const* d_in, const int* in_sizes, int n_in,
                              void* d_out, int out_size, void* d_ws, size_t ws_size,
                              hipStream_t stream) {
  (void)in_sizes; (void)n_in; (void)out_size; (void)ws_size;
  const float* inp = (const float*)d_in[0];
  const float* hx  = (const float*)d_in[1];
  const float* s0  = (const float*)d_in[2];
  const float* s1  = (const float*)d_in[3];
  const float* Wo  = (const float*)d_in[4];
  const float* bo  = (const float*)d_in[5];
  const float* Wu  = (const float*)d_in[6];
  const float* bu  = (const float*)d_in[7];
  float* out = (float*)d_out;

  char* p = (char*)d_ws;
  u16* Sb0 = (u16*)p; p += (size_t)NN * NN * 2;
  u16* Sb1 = (u16*)p; p += (size_t)NN * NN * 2;
  u16* SSb0 = (u16*)p; p += (size_t)NN * NN * 2;
  u16* SSb1 = (u16*)p; p += (size_t)NN * NN * 2;
  const size_t xbytes = (size_t)NCOLS * NN * 2;
  u16* X0T = (u16*)p; p += xbytes;
  u16* X1T = (u16*)p; p += xbytes;
  u16* X2T = (u16*)p; p += xbytes;
  u16* X3T = (u16*)p; p += xbytes;
  u16* X4T = (u16*)p; p += xbytes;
  u16* X0P = (u16*)p; p += xbytes;
  u16* WF1 = (u16*)p; p += (size_t)11 * 8 * 512 * 2;  // 90112 B
  u16* WF2 = (u16*)p; p += (size_t)11 * 4 * 512 * 2;  // 45056 B
  // ST scratch: X1T/X3T are not written until gconv1, free for sq_gemm input.
  u16* ST0 = X1T;
  u16* ST1 = X3T;
  // total ws use: 8 MB + 6*8.25 MB + ~132 KB

  // one pack launch: supports (512 blocks) + X0^T (1024) + WF (33)
  pack_all<<<dim3(1569), dim3(256), 0, stream>>>(
      s0, s1, inp, hx, Wo, Wu, Sb0, Sb1, ST0, ST1, X0T, X0P, WF1, WF2);
  sq_gemm<<<dim3(128), dim3(256), 0, stream>>>(Sb0, Sb1, ST0, ST1, SSb0, SSb1);
  // gconv1: X1=S0 X0, X3=S1 X0, Y2=SS0 X0, Y4=SS1 X0 (one launch; fold in WF)
  gconv_gemm<<<dim3(1056), dim3(256), 0, stream>>>(Sb0, Sb1, SSb0, SSb1, X0T,
                                                   X1T, X2T, X3T, X4T);
  proj1<<<dim3(16, 64), dim3(256), 0, stream>>>(X0T, X1T, X2T, X3T, X4T, WF1, bo, hx, X0P, out);
  // gconv2 on X0'
  gconv_gemm<<<dim3(1056), dim3(256), 0, stream>>>(Sb0, Sb1, SSb0, SSb1, X0P,
                                                   X1T, X2T, X3T, X4T);
  proj2<<<dim3(16, 64), dim3(256), 0, stream>>>(X0P, X1T, X2T, X3T, X4T, WF2, bu, hx, out, out);
}